// Round 5
// baseline (14531.752 us; speedup 1.0000x reference)
//
#include <hip/hip_runtime.h>

// VanillaRNN: BATCH=1024, SEQ=512, HID=512, OUT=10
// h <- tanh(W_hh @ h + W_hx x_t + b_h), 512 steps, then y = W_yh h + b_y.
//
// Round 9 = hardened Round 8 (container died with no diagnostics; suspects:
// untimed spin-wait hang / coherence-stale spin / cooperative+capture).
// Design unchanged: split M across CU PAIRS (128 WGs, cooperative). Each WG
// owns 256 rows -> ALL of its W in registers (128 VGPR), zero W-LDS traffic,
// LDS only 16KB of h double-buffer. Per step, pair exchanges 8KB h-halves
// through LLC with device-scope flags.
// Hardening:
//   * spin-wait TIMEOUT (~0.2s via s_memrealtime) + sticky 'dead' flag:
//     converts any sync failure into a fast wrong-answer instead of a GPU
//     hang. Dead WGs still post flags, so partners never wedge.
//   * exchange-data stores are AGENT-scope relaxed 8B atomic stores: data
//     reaches the LLC coherence point unconditionally (no reliance on
//     release-store L2 writeback). threadfence + barrier before flag release.
//   * s_sleep(8) in spin loops (64Ki threads otherwise hammer 2 LLC lines).
//
// ws: [0,1MB) hG | [1MB,1.5MB) W A-frags | [1.5MB,3.5MB) h exchange buf
//     | [3.5MB,+512B) flags (memset to 0 each launch). Needs ws >= 3.5MB+4KB.

#define BATCH 1024
#define SEQT  512
#define HID   512
#define OUTD  10

typedef _Float16 f16;
typedef _Float16 f16x8 __attribute__((ext_vector_type(8)));
typedef _Float16 f16x4 __attribute__((ext_vector_type(4)));
typedef float    f32x4 __attribute__((ext_vector_type(4)));

// W_hh fp32 [H][H] -> fp16 A-fragment layout:
// entry (rg*16+kk)*64+lane = f16x8 of A[m][k],
// m = rg*16+(lane&15), k = kk*32+((lane>>4)&3)*8+j.   (rg = row/16)
__global__ void wconv_kernel(const float* __restrict__ Whh, f16* __restrict__ frag) {
    int id = blockIdx.x * blockDim.x + threadIdx.x;   // 0..32767
    int lane = id & 63;
    int kk   = (id >> 6) & 15;
    int rg   = id >> 10;                              // 0..31
    int m = rg * 16 + (lane & 15);
    int k = kk * 32 + ((lane >> 4) & 3) * 8;
    const float* src = Whh + (size_t)m * HID + k;
    f16x8 v;
#pragma unroll
    for (int j = 0; j < 8; ++j) v[j] = (f16)src[j];
    *(f16x8*)(frag + (size_t)id * 8) = v;
}

__device__ __forceinline__ float fast_tanh(float v) {
    v = fminf(fmaxf(v, -15.f), 15.f);
    float e = __expf(2.f * v);
    return (e - 1.f) * __builtin_amdgcn_rcpf(e + 1.f);
}

__global__ __launch_bounds__(512)
__attribute__((amdgpu_waves_per_eu(2, 2)))
void rnn_pair(
    const f16* __restrict__ frag,   // W_hh A-frags
    f16* __restrict__ hG,           // final h, frag-blocked
    const float* __restrict__ x,    // [B][T]
    const float* __restrict__ Whx,  // [H]
    const float* __restrict__ bh,   // [H]
    f16* __restrict__ gbuf,         // [64 cg][2 parity][8192 f16] exchange
    int* __restrict__ flags)        // [128], 0-init each launch
{
    __shared__ f16 HB[2][4096];     // own-half h, local B-frag layout, 16 KB

    const int tid  = threadIdx.x;
    const int w    = tid >> 6;       // wave -> own row-block of 32 rows
    const int lane = tid & 63;
    const int n    = lane & 15;
    const int q    = lane >> 4;
    const int bid  = blockIdx.x;
    const int cg   = bid & 63;       // batch col-group: cols [cg*16,+16)
    const int p    = bid >> 6;       // row half: rows [p*256,+256)
    const int partner = bid ^ 64;    // same cg, other half

    // ---- own-half h(0) = 0 ----
    {
        f16x8 z;
#pragma unroll
        for (int j = 0; j < 8; ++j) z[j] = (f16)0.f;
        *(f16x8*)&HB[0][tid * 8] = z;
    }

    const f16x8* A = (const f16x8*)frag;

    // ---- ALL of this WG's W in registers: 32 frags = 128 VGPRs.
    // i 0..7: own-half kk = p*8+i; i 8..15: partner-half kk = (p^1)*8+(i-8).
    f16x8 Wr[32];
#pragma unroll
    for (int i = 0; i < 16; ++i) {
        int kkg = (i < 8) ? (p * 8 + i) : ((p ^ 1) * 8 + (i - 8));
#pragma unroll
        for (int mtl = 0; mtl < 2; ++mtl) {
            int rg = p * 16 + w * 2 + mtl;
            Wr[i * 2 + mtl] = A[(rg * 16 + kkg) * 64 + lane];
        }
    }

    // ---- Whx/bh hoisted as f16 (8 regs) ----
    f16x4 wx_h[2], bh_h[2];
#pragma unroll
    for (int mtl = 0; mtl < 2; ++mtl) {
        int m0 = p * 256 + w * 32 + mtl * 16 + q * 4;
        f32x4 w4 = *(const f32x4*)(Whx + m0);
        f32x4 b4 = *(const f32x4*)(bh + m0);
#pragma unroll
        for (int r = 0; r < 4; ++r) {
            wx_h[mtl][r] = (f16)w4[r];
            bh_h[mtl][r] = (f16)b4[r];
        }
    }

    __syncthreads();

    const float* xp = x + (size_t)(cg * 16 + n) * SEQT;

    f16x8 Pb[8];                    // partner-half h, in registers
#pragma unroll
    for (int i = 0; i < 8; ++i)
#pragma unroll
        for (int j = 0; j < 8; ++j) Pb[i][j] = (f16)0.f;   // h(0) = 0

    int dead = 0;                   // sticky: partner unresponsive -> no hangs

#pragma unroll 1
    for (int s = 0; s < SEQT; ++s) {
        float xv = xp[s];

        // phase A: own half from LDS (8 pipelined ds_read_b128)
        const f16* hr = &HB[s & 1][0];
        f16x8 bfA[8];
#pragma unroll
        for (int i = 0; i < 8; ++i)
            bfA[i] = *(const f16x8*)&hr[(i * 64 + lane) * 8];

        f32x4 acc0 = {0, 0, 0, 0}, acc1 = {0, 0, 0, 0};
#pragma unroll
        for (int i = 0; i < 8; ++i) {
            acc0 = __builtin_amdgcn_mfma_f32_16x16x32_f16(Wr[i * 2],     bfA[i], acc0, 0, 0, 0);
            acc1 = __builtin_amdgcn_mfma_f32_16x16x32_f16(Wr[i * 2 + 1], bfA[i], acc1, 0, 0, 0);
        }
        // phase B: partner half from registers (loaded last step, latency
        // hidden under phase A)
#pragma unroll
        for (int i = 0; i < 8; ++i) {
            acc0 = __builtin_amdgcn_mfma_f32_16x16x32_f16(Wr[(8 + i) * 2],     Pb[i], acc0, 0, 0, 0);
            acc1 = __builtin_amdgcn_mfma_f32_16x16x32_f16(Wr[(8 + i) * 2 + 1], Pb[i], acc1, 0, 0, 0);
        }

        // ---- epilogue: tanh; own half -> HB(next parity) + gbuf(LLC) ----
        // row m = p*256 + w*32 + mtl*16 + q*4 + r -> kkG = p*8+w,
        // q2 = mtl*2+(q>>1), j0 = (q&1)*4, col n.
        f16* hw = &HB[(s + 1) & 1][0];
        f16* gw = gbuf + ((size_t)(cg * 2) + ((s + 1) & 1)) * 8192;
#pragma unroll
        for (int mtl = 0; mtl < 2; ++mtl) {
            f16x4 hv;
#pragma unroll
            for (int r = 0; r < 4; ++r) {
                float a = (mtl == 0) ? acc0[r] : acc1[r];
                float pre = fmaf((float)wx_h[mtl][r], xv, a) + (float)bh_h[mtl][r];
                hv[r] = (f16)fast_tanh(pre);
            }
            int q2 = mtl * 2 + (q >> 1);
            int j0 = (q & 1) * 4;
            if (s < SEQT - 1) {
                *(f16x4*)&hw[(w * 64 + q2 * 16 + n) * 8 + j0] = hv;
                // agent-scope store: data goes to the LLC coherence point,
                // independent of any release-writeback subtleties.
                union { f16x4 h; unsigned long long u; } cv; cv.h = hv;
                __hip_atomic_store(
                    (unsigned long long*)(gw + ((p * 8 + w) * 64 + q2 * 16 + n) * 8 + j0),
                    cv.u, __ATOMIC_RELAXED, __HIP_MEMORY_SCOPE_AGENT);
            } else {
                *(f16x4*)(hG + (size_t)(((cg * 16 + p * 8 + w) * 64 + q2 * 16 + n) * 8 + j0)) = hv;
            }
        }

        if (s < SEQT - 1) {
            __threadfence();     // agent fence: this thread's stores visible
            __syncthreads();     // + vmcnt drain for the whole WG
            if (tid == 0)
                __hip_atomic_store(&flags[bid], s + 1,
                                   __ATOMIC_RELEASE, __HIP_MEMORY_SCOPE_AGENT);
            if (!dead) {
                const int tgt = s + 1;
                unsigned long long t0 = __builtin_amdgcn_s_memrealtime();
                while (__hip_atomic_load(&flags[partner], __ATOMIC_ACQUIRE,
                                         __HIP_MEMORY_SCOPE_AGENT) < tgt) {
                    __builtin_amdgcn_s_sleep(8);
                    if (__builtin_amdgcn_s_memrealtime() - t0 > 20000000ull) {
                        dead = 1;   // ~0.2s: partner gone; finish with garbage
                        break;      // (fast passed:false beats a dead container)
                    }
                }
            }
            // partner half h(s+1) -> registers; consumed at the END of next
            // step's MFMA work, so LLC latency hides under phase A.
            const f16* gr = gbuf + ((size_t)(cg * 2) + ((s + 1) & 1)) * 8192;
#pragma unroll
            for (int i = 0; i < 8; ++i)
                Pb[i] = *(const f16x8*)(gr + (((p ^ 1) * 8 + i) * 64 + lane) * 8);
        }
    }
}

// out[b][o] = by[o] + sum_k Wyh[o][k] * h[b][k], h in frag-blocked layout.
__global__ __launch_bounds__(256) void y_kernel(
    const f16* __restrict__ h, const float* __restrict__ Wyh,
    const float* __restrict__ by, float* __restrict__ out)
{
    int id = blockIdx.x * blockDim.x + threadIdx.x;
    if (id >= BATCH * OUTD) return;
    int b = id / OUTD, o = id % OUTD;
    int bg = b >> 4, n = b & 15;
    const float* wrow = Wyh + (size_t)o * HID;
    float s = by[o];
    for (int kk = 0; kk < 16; ++kk)
#pragma unroll
        for (int q2 = 0; q2 < 4; ++q2) {
            f16x8 hv = *(const f16x8*)(h + (size_t)((bg * 16 + kk) * 64 + q2 * 16 + n) * 8);
            const float* wp = wrow + kk * 32 + q2 * 8;
#pragma unroll
            for (int j = 0; j < 8; ++j) s += wp[j] * (float)hv[j];
        }
    out[id] = s;
}

extern "C" void kernel_launch(void* const* d_in, const int* in_sizes, int n_in,
                              void* d_out, int out_size, void* d_ws, size_t ws_size,
                              hipStream_t stream) {
    const float* x   = (const float*)d_in[0];
    const float* Whx = (const float*)d_in[1];
    const float* Whh = (const float*)d_in[2];
    const float* Wyh = (const float*)d_in[3];
    const float* bh  = (const float*)d_in[4];
    const float* by  = (const float*)d_in[5];
    float* out = (float*)d_out;

    char* ws    = (char*)d_ws;
    f16*  hG    = (f16*)ws;                           // 1 MB @ 0
    f16*  frag  = (f16*)(ws + (1 << 20));             // 512 KB @ 1MB
    f16*  gbuf  = (f16*)(ws + (1 << 20) + (1 << 19)); // 2 MB @ 1.5MB
    int*  flags = (int*)(ws + (7 << 19));             // 512 B @ 3.5MB

    hipMemsetAsync(flags, 0, 128 * sizeof(int), stream);
    wconv_kernel<<<128, 256, 0, stream>>>(Whh, frag);

    void* args[] = {(void*)&frag, (void*)&hG, (void*)&x, (void*)&Whx,
                    (void*)&bh, (void*)&gbuf, (void*)&flags};
    hipLaunchCooperativeKernel(rnn_pair, dim3(128), dim3(512), args, 0, stream);

    y_kernel<<<(BATCH * OUTD + 255) / 256, 256, 0, stream>>>(hG, Wyh, by, out);
}

// Round 6
// 1627.503 us; speedup vs baseline: 8.9289x; 8.9289x over previous
//
#include <hip/hip_runtime.h>

// VanillaRNN: BATCH=1024, SEQ=512, HID=512, OUT=10
// h <- tanh(W_hh @ h + W_hx x_t + b_h), 512 steps, then y = W_yh h + b_y.
//
// Round 10: R9 proved cross-CU h-exchange costs >= the whole step (850MB
// uncached LLC traffic, 28us/step) -> W must be CU-resident, 64 WGs forced.
// R4-R7 proved the 8-wave config is register-capacity-deadlocked (8 spare
// VGPRs -> ds_read latency fully exposed, 5900cyc step vs ~2700 DS floor).
// Exit: SAME capacity, DIFFERENT partition. 256 threads = 4 waves at
// 1 wave/SIMD with waves_per_eu(1,1) -> 512 VGPRs/wave:
//   * each wave owns 128 rows; 6/8 of W in regs (Wr[96]=384 VGPR),
//     2/8 in LDS (128KB). ~45 VGPRs of slack remain.
//   * h B-frag reads drop 8->4 waves: DS instrs 288->224/CU/step (-25%).
//   * slack funds an EXPLICIT depth-3 load rotation (bfp/a6p/a7p): each
//     ds_read issues ~117cyc (3 MFMA groups) before its use -> latency
//     covered, which R4-R7 could never do.
//   * Whx/bh pre-packed as f16 pairs (prep kernel) -> 8x16B epilogue loads,
//     per-step behind an anti-LICM clobber; opaque-zero offset stops WL
//     frag hoisting (128 regs -> would spill).
//
// ws: [0,1MB) hG | [1MB,1.5MB) W A-frags | [1.5MB,+2KB) wxbh f16 pairs.

#define BATCH 1024
#define SEQT  512
#define HID   512
#define OUTD  10

typedef _Float16 f16;
typedef _Float16 f16x8 __attribute__((ext_vector_type(8)));
typedef _Float16 f16x4 __attribute__((ext_vector_type(4)));
typedef float    f32x4 __attribute__((ext_vector_type(4)));

// W_hh fp32 [H][H] -> fp16 A-fragment layout (same as R9, HW-verified):
// entry (rg*16+kk)*64+lane = f16x8 of A[m][k],
// m = rg*16+(lane&15), k = kk*32+((lane>>4)&3)*8+j.   (rg = row/16)
__global__ void wconv_kernel(const float* __restrict__ Whh, f16* __restrict__ frag) {
    int id = blockIdx.x * blockDim.x + threadIdx.x;   // 0..32767
    int lane = id & 63;
    int kk   = (id >> 6) & 15;
    int rg   = id >> 10;                              // 0..31
    int m = rg * 16 + (lane & 15);
    int k = kk * 32 + ((lane >> 4) & 3) * 8;
    const float* src = Whh + (size_t)m * HID + k;
    f16x8 v;
#pragma unroll
    for (int j = 0; j < 8; ++j) v[j] = (f16)src[j];
    *(f16x8*)(frag + (size_t)id * 8) = v;
}

// pack Whx/bh as interleaved f16 pairs: wxbh[2m]=Whx[m], wxbh[2m+1]=bh[m]
__global__ void prep_kernel(const float* __restrict__ Whx,
                            const float* __restrict__ bh,
                            f16* __restrict__ wxbh) {
    int m = blockIdx.x * blockDim.x + threadIdx.x;
    if (m < HID) {
        wxbh[2 * m]     = (f16)Whx[m];
        wxbh[2 * m + 1] = (f16)bh[m];
    }
}

__device__ __forceinline__ float fast_tanh(float v) {
    v = fminf(fmaxf(v, -15.f), 15.f);
    float e = __expf(2.f * v);
    return (e - 1.f) * __builtin_amdgcn_rcpf(e + 1.f);
}

__global__ __launch_bounds__(256)
__attribute__((amdgpu_waves_per_eu(1, 1)))
void rnn_cu(
    const f16* __restrict__ frag,   // W_hh A-frags (rg-blocked)
    f16* __restrict__ hG,           // final h, frag-blocked [64][16][64][8]
    const float* __restrict__ x,    // [B][T]
    const f16* __restrict__ wxbh)   // [H][2] f16 {Whx, bh}
{
    __shared__ f16 HB[2][8192];     // double-buffered h, B-frag layout, 32 KB
    __shared__ f16 WL[65536];       // W A-frags, mt 6..7 per wave, 128 KB

    const int tid  = threadIdx.x;
    const int w    = tid >> 6;       // wave -> row-block of 128 rows
    const int lane = tid & 63;
    const int n    = lane & 15;
    const int q    = lane >> 4;
    const int bg   = blockIdx.x;     // batch cols [bg*16, +16)

    // ---- h(0) = 0 (buffer 0 read at s=0): 8192 f16 over 256 threads ----
    {
        f16x8 z;
#pragma unroll
        for (int j = 0; j < 8; ++j) z[j] = (f16)0.f;
#pragma unroll
        for (int i = 0; i < 4; ++i) *(f16x8*)&HB[0][tid * 32 + i * 8] = z;
    }

    const f16x8* A = (const f16x8*)frag;

    // ---- WL: entry e = (slot*16+kk)*64+ln, slot = w*2 + (mt-6) ----
#pragma unroll
    for (int i = 0; i < 32; ++i) {
        int e    = i * 256 + tid;
        int slot = e >> 10;
        int kk   = (e >> 6) & 15;
        int ln   = e & 63;
        int rg   = (slot >> 1) * 8 + 6 + (slot & 1);
        *(f16x8*)&WL[(size_t)e * 8] = A[(rg * 16 + kk) * 64 + ln];
    }

    // ---- register W: mt 0..5, kk-major (384 VGPRs) ----
    f16x8 Wr[96];
#pragma unroll
    for (int kk = 0; kk < 16; ++kk)
#pragma unroll
        for (int mt = 0; mt < 6; ++mt)
            Wr[kk * 6 + mt] = A[((w * 8 + mt) * 16 + kk) * 64 + lane];

    __syncthreads();

    const float* xp = x + (size_t)(bg * 16 + n) * SEQT;
    const int a6base = (w * 2) * 1024 + lane;       // + kk*64 per entry
    const int a7base = (w * 2 + 1) * 1024 + lane;

#pragma unroll 1
    for (int s = 0; s < SEQT; ++s) {
        const f16* hbr = &HB[s & 1][0];
        f16*       hbw = &HB[(s & 1) ^ 1][0];
        float xv = xp[s];

        // opaque zero: WL reads are loop-invariant; without this the
        // compiler hoists 32 frags (128 regs) out of the s-loop -> spill.
        int wo = 0;
        asm volatile("" : "+v"(wo));

        f32x4 acc[8];
#pragma unroll
        for (int mt = 0; mt < 8; ++mt) acc[mt] = (f32x4){0.f, 0.f, 0.f, 0.f};

        // ---- depth-3 rotation: each read issues ~3 MFMA groups early ----
        f16x8 bfp[3], a6p[3], a7p[3];
#pragma unroll
        for (int i = 0; i < 3; ++i) {
            bfp[i] = *(const f16x8*)&hbr[(i * 64 + lane) * 8];
            a6p[i] = *(const f16x8*)&WL[(size_t)(a6base + i * 64 + wo) * 8];
            a7p[i] = *(const f16x8*)&WL[(size_t)(a7base + i * 64 + wo) * 8];
        }

#pragma unroll
        for (int kk = 0; kk < 16; ++kk) {
            const int c = kk % 3;
#pragma unroll
            for (int mt = 0; mt < 6; ++mt)
                acc[mt] = __builtin_amdgcn_mfma_f32_16x16x32_f16(
                    Wr[kk * 6 + mt], bfp[c], acc[mt], 0, 0, 0);
            acc[6] = __builtin_amdgcn_mfma_f32_16x16x32_f16(a6p[c], bfp[c], acc[6], 0, 0, 0);
            acc[7] = __builtin_amdgcn_mfma_f32_16x16x32_f16(a7p[c], bfp[c], acc[7], 0, 0, 0);
            if (kk < 13) {   // prefetch kk+3 into the slot just consumed
                bfp[c] = *(const f16x8*)&hbr[((kk + 3) * 64 + lane) * 8];
                a6p[c] = *(const f16x8*)&WL[(size_t)(a6base + (kk + 3) * 64 + wo) * 8];
                a7p[c] = *(const f16x8*)&WL[(size_t)(a7base + (kk + 3) * 64 + wo) * 8];
            }
        }

        // ---- epilogue: wxbh loads (16B x8, L1-hot, anti-LICM), tanh,
        //      write h(s+1) in B-frag layout ----
        const f16* wp = wxbh;
        asm volatile("" : "+v"(wp));
        f16x8 wb[8];
#pragma unroll
        for (int mt = 0; mt < 8; ++mt)
            wb[mt] = *(const f16x8*)(wp + (size_t)(w * 128 + mt * 16 + q * 4) * 2);

        // row m = w*128 + mt*16 + q*4 + r -> kkb = w*4+(mt>>1),
        // hi = (mt&1)*2+(q>>1), j0 = (q&1)*4, col n.
#pragma unroll
        for (int mt = 0; mt < 8; ++mt) {
            f16x4 hv;
#pragma unroll
            for (int r = 0; r < 4; ++r) {
                float pre = fmaf((float)wb[mt][2 * r], xv, acc[mt][r])
                          + (float)wb[mt][2 * r + 1];
                hv[r] = (f16)fast_tanh(pre);
            }
            int kkb = w * 4 + (mt >> 1);
            int hi  = (mt & 1) * 2 + (q >> 1);
            int j0  = (q & 1) * 4;
            int off = (kkb * 64 + hi * 16 + n) * 8 + j0;
            if (s < SEQT - 1) {
                *(f16x4*)&hbw[off] = hv;
            } else {
                *(f16x4*)(hG + (size_t)(((bg * 16 + kkb) * 64 + hi * 16 + n) * 8 + j0)) = hv;
            }
        }

        __syncthreads();   // h(s+1) complete before next step's reads
    }
}

// out[b][o] = by[o] + sum_k Wyh[o][k] * h[b][k], h in frag-blocked layout.
__global__ __launch_bounds__(256) void y_kernel(
    const f16* __restrict__ h, const float* __restrict__ Wyh,
    const float* __restrict__ by, float* __restrict__ out)
{
    int id = blockIdx.x * blockDim.x + threadIdx.x;
    if (id >= BATCH * OUTD) return;
    int b = id / OUTD, o = id % OUTD;
    int bg = b >> 4, n = b & 15;
    const float* wrow = Wyh + (size_t)o * HID;
    float s = by[o];
    for (int kk = 0; kk < 16; ++kk)
#pragma unroll
        for (int q2 = 0; q2 < 4; ++q2) {
            f16x8 hv = *(const f16x8*)(h + (size_t)((bg * 16 + kk) * 64 + q2 * 16 + n) * 8);
            const float* wp = wrow + kk * 32 + q2 * 8;
#pragma unroll
            for (int j = 0; j < 8; ++j) s += wp[j] * (float)hv[j];
        }
    out[id] = s;
}

extern "C" void kernel_launch(void* const* d_in, const int* in_sizes, int n_in,
                              void* d_out, int out_size, void* d_ws, size_t ws_size,
                              hipStream_t stream) {
    const float* x   = (const float*)d_in[0];
    const float* Whx = (const float*)d_in[1];
    const float* Whh = (const float*)d_in[2];
    const float* Wyh = (const float*)d_in[3];
    const float* bh  = (const float*)d_in[4];
    const float* by  = (const float*)d_in[5];
    float* out = (float*)d_out;

    char* ws   = (char*)d_ws;
    f16*  hG   = (f16*)ws;                        // 1 MB @ 0
    f16*  frag = (f16*)(ws + (1 << 20));          // 512 KB @ 1MB
    f16*  wxbh = (f16*)(ws + (3 << 19));          // 2 KB @ 1.5MB

    wconv_kernel<<<128, 256, 0, stream>>>(Whh, frag);
    prep_kernel<<<2, 256, 0, stream>>>(Whx, bh, wxbh);
    rnn_cu<<<64, 256, 0, stream>>>(frag, hG, x, wxbh);
    y_kernel<<<(BATCH * OUTD + 255) / 256, 256, 0, stream>>>(hG, Wyh, by, out);
}